// Round 13
// baseline (189.037 us; speedup 1.0000x reference)
//
#include <hip/hip_runtime.h>
#include <hip/hip_bf16.h>
#include <hip/hip_fp16.h>

#define D_MODEL 768
#define NHEADS  12
#define HD      64
#define BATCH   2
#define SEQ     2048
#define NTOK    (BATCH*SEQ)   // 4096
#define NX      ((size_t)NTOK * D_MODEL)     // 3,145,728
#define NW      ((size_t)D_MODEL * D_MODEL)  // 589,824
#define SC_LOG2 0.18033688f   // (1/8) * log2(e), folded into Wq/bq

typedef __attribute__((ext_vector_type(8))) short    short8;
typedef __attribute__((ext_vector_type(8))) _Float16 half8;
typedef __attribute__((ext_vector_type(2))) __fp16   fp16x2;
typedef __attribute__((ext_vector_type(4))) float    f32x4;

__device__ __forceinline__ float bf2f(short s) {
    union { unsigned u; float f; } c;
    c.u = ((unsigned)(unsigned short)s) << 16;
    return c.f;
}
__device__ __forceinline__ short f2bf(float f) {
    __hip_bfloat16 h = __float2bfloat16(f);
    return *(short*)&h;
}

#ifdef __has_builtin
#if __has_builtin(__builtin_amdgcn_global_load_lds)
#define HAS_GLD 1
#endif
#if __has_builtin(__builtin_amdgcn_exp2f)
#define EXP2(x) __builtin_amdgcn_exp2f(x)
#else
#define EXP2(x) exp2f(x)
#endif
#if __has_builtin(__builtin_amdgcn_cvt_pkrtz)
#define HAS_PKRTZ 1
#endif
#else
#define EXP2(x) exp2f(x)
#endif
#ifdef HAS_GLD
#define GLD16(gp, lp) __builtin_amdgcn_global_load_lds( \
    (const __attribute__((address_space(1))) void*)(gp), \
    (__attribute__((address_space(3))) void*)(lp), 16, 0, 0)
#endif

// ---------------------------------------------------------------------------
// Fused conversion kernel (one launch): every block locally detects the input
// dtype from x's first 4096 halfwords, then converts its assigned slice.
//   blocks [0,3072):   x -> bf16 (int4-wide)
//   blocks [3072,3648): weight transpose+convert (Wq scaled by SC_LOG2)
//   block 3648:        biases (bq scaled) + persist flag for out_gemm
// ---------------------------------------------------------------------------
__global__ __launch_bounds__(256) void fused_conv(
        const void* __restrict__ xin,
        const void* __restrict__ w0, const void* __restrict__ w1,
        const void* __restrict__ w2, const void* __restrict__ w3,
        const void* __restrict__ b0, const void* __restrict__ b1,
        const void* __restrict__ b2, const void* __restrict__ b3,
        short* __restrict__ xc, short* __restrict__ wt,
        short* __restrict__ bc, int* __restrict__ flag)
{
    __shared__ int red[256];
    __shared__ float T[64][65];
    const int tid = threadIdx.x;
    const int F = blockIdx.x;

    {
        const short* xs = (const short*)xin;
        int maxe = 0;
#pragma unroll
        for (int u = 0; u < 16; ++u) {
            int e = ((unsigned short)xs[tid * 16 + u] >> 7) & 0xFF;
            maxe = max(maxe, e);
        }
        red[tid] = maxe;
        __syncthreads();
        for (int s = 128; s > 0; s >>= 1) {
            if (tid < s) red[tid] = max(red[tid], red[tid + s]);
            __syncthreads();
        }
    }
    const bool isf = (red[0] > 140);

    if (F < 3072) {
        const int i = F * 256 + tid;
        if (isf) {
            float4 f = ((const float4*)xin)[i];
            short4 o = { f2bf(f.x), f2bf(f.y), f2bf(f.z), f2bf(f.w) };
            ((short4*)xc)[i] = o;
        } else {
            ((short4*)xc)[i] = ((const short4*)xin)[i];
        }
    } else if (F < 3648) {
        const int G = F - 3072;
        const int z = G / 144, rr = G % 144;
        const int k0 = (rr % 12) * 64, n0 = (rr / 12) * 64;
        const void* src = (z == 0) ? w0 : (z == 1) ? w1 : (z == 2) ? w2 : w3;
        const float sc = (z == 0) ? SC_LOG2 : 1.0f;
        const int la = tid & 15, lb = tid >> 4;
#pragma unroll
        for (int u = 0; u < 4; ++u) {
            const int kr = (lb & 3) + 4 * u + 16 * (lb >> 2);
            if (isf) {
                float4 f = *(const float4*)((const float*)src + (size_t)(k0 + kr) * D_MODEL + n0 + la * 4);
                T[kr][la*4+0] = f.x; T[kr][la*4+1] = f.y; T[kr][la*4+2] = f.z; T[kr][la*4+3] = f.w;
            } else {
                short4 s = *(const short4*)((const short*)src + (size_t)(k0 + kr) * D_MODEL + n0 + la * 4);
                T[kr][la*4+0] = bf2f(s.x); T[kr][la*4+1] = bf2f(s.y);
                T[kr][la*4+2] = bf2f(s.z); T[kr][la*4+3] = bf2f(s.w);
            }
        }
        __syncthreads();
#pragma unroll
        for (int u = 0; u < 4; ++u) {
            const int nr = (lb & 3) + 4 * u + 16 * (lb >> 2);
            short4 o = { f2bf(T[la*4+0][nr] * sc), f2bf(T[la*4+1][nr] * sc),
                         f2bf(T[la*4+2][nr] * sc), f2bf(T[la*4+3][nr] * sc) };
            *(short4*)(wt + (size_t)z * NW + (size_t)(n0 + nr) * D_MODEL + k0 + la * 4) = o;
        }
    } else {
        if (tid == 0) *flag = isf ? 1 : 0;
        const void* srcs[4] = { b0, b1, b2, b3 };
        for (int z = 0; z < 4; ++z) {
            const float sc = (z == 0) ? SC_LOG2 : 1.0f;
            for (int i = tid; i < D_MODEL; i += 256) {
                float v = isf ? ((const float*)srcs[z])[i] : bf2f(((const short*)srcs[z])[i]);
                bc[z * D_MODEL + i] = f2bf(v * sc);
            }
        }
    }
}

// ---------------------------------------------------------------------------
// Fused QKV GEMM (R8 version), double-buffered GLD16 both sides:
// OUT[4096][2304] = X @ [Wq|Wk|Wv] + bias. V segment -> Vt f16 [bh][dim][SEQ].
// ---------------------------------------------------------------------------
__global__ __launch_bounds__(256) void qkv_gemm(const short* __restrict__ X,
                                                const short* __restrict__ Wt,
                                                const short* __restrict__ bias,
                                                short* __restrict__ qb,
                                                short* __restrict__ kb,
                                                _Float16* __restrict__ Vt)
{
    __shared__ __align__(16) char shbuf[32768];
    short* Als = (short*)shbuf;              // [2][4096]
    short* Bls = (short*)(shbuf + 16384);    // [2][4096]
    _Float16* T = (_Float16*)shbuf;          // epilogue: 64*136 f16

    const int tid = threadIdx.x;
    const int wave = tid >> 6, lane = tid & 63;
    const int quad = lane >> 4, l16 = lane & 15;
    const int wm = wave & 1, wn = wave >> 1;
    const int m0 = blockIdx.x * 128;
    const int ng = blockIdx.y * 128;

    f32x4 acc[4][4];
#pragma unroll
    for (int nt = 0; nt < 4; ++nt) {
        const float bv = bf2f(bias[ng + wn*64 + nt*16 + l16]);
#pragma unroll
        for (int mt = 0; mt < 4; ++mt) acc[mt][nt] = (f32x4){bv, bv, bv, bv};
    }

    const int row = tid >> 2, ch = (tid & 3) * 8;
#ifdef HAS_GLD
#define QSTAGE(buf, k0) do { \
        GLD16(X  + (size_t)(m0 + row)      * D_MODEL + (k0) + ch, &Als[(buf)*4096 + tid*8]); \
        GLD16(X  + (size_t)(m0 + 64 + row) * D_MODEL + (k0) + ch, &Als[(buf)*4096 + 2048 + tid*8]); \
        GLD16(Wt + (size_t)(ng + row)      * D_MODEL + (k0) + ch, &Bls[(buf)*4096 + tid*8]); \
        GLD16(Wt + (size_t)(ng + 64 + row) * D_MODEL + (k0) + ch, &Bls[(buf)*4096 + 2048 + tid*8]); \
    } while (0)
#else
#define QSTAGE(buf, k0) do { \
        short8 r0 = *(const short8*)(X  + (size_t)(m0 + row)      * D_MODEL + (k0) + ch); \
        short8 r1 = *(const short8*)(X  + (size_t)(m0 + 64 + row) * D_MODEL + (k0) + ch); \
        short8 r2 = *(const short8*)(Wt + (size_t)(ng + row)      * D_MODEL + (k0) + ch); \
        short8 r3 = *(const short8*)(Wt + (size_t)(ng + 64 + row) * D_MODEL + (k0) + ch); \
        *(short8*)&Als[(buf)*4096 + tid*8] = r0;  *(short8*)&Als[(buf)*4096 + 2048 + tid*8] = r1; \
        *(short8*)&Bls[(buf)*4096 + tid*8] = r2;  *(short8*)&Bls[(buf)*4096 + 2048 + tid*8] = r3; \
    } while (0)
#endif

    QSTAGE(0, 0);
    __syncthreads();

    for (int ks = 0; ks < 24; ++ks) {
        const int cur = ks & 1;
        if (ks + 1 < 24) QSTAGE(cur ^ 1, (ks + 1) * 32);

        short8 a[4], b[4];
#pragma unroll
        for (int mt = 0; mt < 4; ++mt)
            a[mt] = *(const short8*)&Als[cur*4096 + (wm*64 + mt*16 + l16) * 32 + quad*8];
#pragma unroll
        for (int nt = 0; nt < 4; ++nt)
            b[nt] = *(const short8*)&Bls[cur*4096 + (wn*64 + nt*16 + l16) * 32 + quad*8];
#pragma unroll
        for (int mt = 0; mt < 4; ++mt)
#pragma unroll
        for (int nt = 0; nt < 4; ++nt)
            acc[mt][nt] = __builtin_amdgcn_mfma_f32_16x16x32_bf16(a[mt], b[nt], acc[mt][nt], 0, 0, 0);

        __syncthreads();
    }
#undef QSTAGE

    const int seg = blockIdx.y / 6;   // 0=q, 1=k, 2=v
    if (seg < 2) {
        short* out = seg ? kb : qb;
        const int nl = ng - seg * 768;
#pragma unroll
        for (int mt = 0; mt < 4; ++mt)
#pragma unroll
        for (int nt = 0; nt < 4; ++nt) {
            const int n = nl + wn*64 + nt*16 + l16;
#pragma unroll
            for (int r = 0; r < 4; ++r) {
                const int m = m0 + wm*64 + mt*16 + quad*4 + r;
                out[(size_t)m * D_MODEL + n] = f2bf(acc[mt][nt][r]);
            }
        }
    } else {
        const int batch = m0 >> 11, tokb = m0 & (SEQ - 1);
        for (int pass = 0; pass < 2; ++pass) {
            if (wn == pass) {
#pragma unroll
                for (int nt = 0; nt < 4; ++nt) {
                    const int dim_l = nt*16 + l16;
#pragma unroll
                    for (int mt = 0; mt < 4; ++mt) {
                        const int tok_l = wm*64 + mt*16 + quad*4;
                        union { _Float16 h4[4]; int2 v; } u;
#pragma unroll
                        for (int r = 0; r < 4; ++r) u.h4[r] = (_Float16)acc[mt][nt][r];
                        *(int2*)&T[dim_l * 136 + tok_l] = u.v;
                    }
                }
            }
            __syncthreads();
#pragma unroll
            for (int u = 0; u < 4; ++u) {
                const int slot = tid + u * 256;
                const int drow = slot >> 4, chk = slot & 15;
                int4 val = *(const int4*)&T[drow * 136 + chk * 8];
                const int dim_g = ng - 1536 + pass*64 + drow;
                const int h = dim_g >> 6, d = dim_g & 63;
                *(int4*)(Vt + ((size_t)(batch * NHEADS + h) * HD + d) * SEQ + tokb + chk*8) = val;
            }
            if (pass == 0) __syncthreads();
        }
    }
}

// ---------------------------------------------------------------------------
// Output projection, 64x64 tiles, double-buffered staging.
// ---------------------------------------------------------------------------
__global__ __launch_bounds__(256) void out_gemm(const short* __restrict__ X,
                                                const short* __restrict__ Wt,
                                                const short* __restrict__ bias,
                                                void* __restrict__ outv,
                                                const int* __restrict__ flag)
{
    __shared__ short Als[2][2048];
    __shared__ short Bls[2][2048];

    const int tid = threadIdx.x;
    const int wave = tid >> 6, lane = tid & 63;
    const int quad = lane >> 4, l16 = lane & 15;
    const int m0 = blockIdx.x * 64;
    const int n0 = blockIdx.y * 64;

    f32x4 acc[4];
#pragma unroll
    for (int nt = 0; nt < 4; ++nt) {
        const float bv = bf2f(bias[n0 + nt*16 + l16]);
        acc[nt] = (f32x4){bv, bv, bv, bv};
    }

    const int row = tid >> 2, ch = (tid & 3) * 8;
#ifdef HAS_GLD
#define OSTAGE(buf, k0) do { \
        GLD16(X  + (size_t)(m0 + row) * D_MODEL + (k0) + ch, &Als[buf][tid*8]); \
        GLD16(Wt + (size_t)(n0 + row) * D_MODEL + (k0) + ch, &Bls[buf][tid*8]); \
    } while (0)
#else
#define OSTAGE(buf, k0) do { \
        short8 r0 = *(const short8*)(X  + (size_t)(m0 + row) * D_MODEL + (k0) + ch); \
        short8 r1 = *(const short8*)(Wt + (size_t)(n0 + row) * D_MODEL + (k0) + ch); \
        *(short8*)&Als[buf][tid*8] = r0; \
        *(short8*)&Bls[buf][tid*8] = r1; \
    } while (0)
#endif

    OSTAGE(0, 0);
    __syncthreads();

    for (int ks = 0; ks < 24; ++ks) {
        const int cur = ks & 1;
        if (ks + 1 < 24) OSTAGE(cur ^ 1, (ks + 1) * 32);

        short8 a = *(const short8*)&Als[cur][(wave*16 + l16) * 32 + quad*8];
#pragma unroll
        for (int nt = 0; nt < 4; ++nt) {
            short8 b = *(const short8*)&Bls[cur][(nt*16 + l16) * 32 + quad*8];
            acc[nt] = __builtin_amdgcn_mfma_f32_16x16x32_bf16(a, b, acc[nt], 0, 0, 0);
        }
        __syncthreads();
    }
#undef OSTAGE

    const bool outf32 = (*flag != 0);
#pragma unroll
    for (int nt = 0; nt < 4; ++nt) {
        const int n = n0 + nt*16 + l16;
#pragma unroll
        for (int r = 0; r < 4; ++r) {
            const int m = m0 + wave*16 + quad*4 + r;
            const size_t idx = (size_t)m * D_MODEL + n;
            if (outf32) ((float*)outv)[idx] = acc[nt][r];
            else        ((short*)outv)[idx] = f2bf(acc[nt][r]);
        }
    }
}

// ---------------------------------------------------------------------------
// Flash attention v13: 2 waves x 32 queries/wave (block = 128 thr, 64 q/block,
// grid 768 unchanged). Each K/V fragment b128 read now feeds TWO MFMAs (qg=0,1)
// -> LDS-pipe work per tile drops ~40% vs R12's 4x16q layout. All swizzles
// identical to R12 ((qg*16+l16)&7 == l16&7). LDS 40 KB -> 4 blocks/CU cap.
// VALU diet kept: exp2-domain logits, lazy __any max, EXP2, cvt_pkrtz,
// MFMA row-sum. XCD-locality swizzle unchanged.
// ---------------------------------------------------------------------------
__global__ __launch_bounds__(128) void attn_mfma(const short* __restrict__ q,
                                                 const short* __restrict__ k,
                                                 const _Float16* __restrict__ Vt,
                                                 short* __restrict__ ctx)
{
    __shared__ short    Kls[2][64 * 64];       // swizzled [key][chunk], 8 KB/buf
    __shared__ _Float16 Vls[2][64 * 64];       // swizzled [dim][chunk], 8 KB/buf
    __shared__ _Float16 Pls[2][32 * 64];       // per-wave [q32][k64], 8 KB

    const int tid  = threadIdx.x;
    const int wave = tid >> 6, lane = tid & 63;
    const int quad = lane >> 4, l16 = lane & 15;

    const int F = blockIdx.x;
    const int xcd = F & 7, slot = F >> 3;
    const int bh = xcd * 3 + (slot >> 5);
    const int q0 = (slot & 31) * 64;
    const int b = bh / NHEADS, h = bh % NHEADS;
    const size_t bS = (size_t)b * SEQ;
    const int qbase = q0 + wave * 32;

    short8 qf[2][2];
#pragma unroll
    for (int qg = 0; qg < 2; ++qg)
#pragma unroll
    for (int k0h = 0; k0h < 2; ++k0h)
        qf[qg][k0h] = *(const short8*)(q + (bS + qbase + qg*16 + l16) * D_MODEL
                                         + h*HD + k0h*32 + quad*8);

    half8 ones;
#pragma unroll
    for (int j = 0; j < 8; ++j) ones[j] = (_Float16)1.0f;

    // staging: 512 slots, 128 threads -> 4 slots each
    int kr[4], kc[4];
#pragma unroll
    for (int u = 0; u < 4; ++u) {
        const int s = tid + u * 128;
        kr[u] = s >> 3;
        kc[u] = (s & 7) ^ (kr[u] & 7);
    }
    const short*    kg0 = k  + (bS + kr[0]) * D_MODEL + h*HD + kc[0]*8;
    const short*    kg1 = k  + (bS + kr[1]) * D_MODEL + h*HD + kc[1]*8;
    const short*    kg2 = k  + (bS + kr[2]) * D_MODEL + h*HD + kc[2]*8;
    const short*    kg3 = k  + (bS + kr[3]) * D_MODEL + h*HD + kc[3]*8;
    const _Float16* vg0 = Vt + ((size_t)bh * HD + kr[0]) * SEQ + kc[0]*8;
    const _Float16* vg1 = Vt + ((size_t)bh * HD + kr[1]) * SEQ + kc[1]*8;
    const _Float16* vg2 = Vt + ((size_t)bh * HD + kr[2]) * SEQ + kc[2]*8;
    const _Float16* vg3 = Vt + ((size_t)bh * HD + kr[3]) * SEQ + kc[3]*8;

#ifdef HAS_GLD
#define STAGE(buf, j0) do { \
        GLD16(kg0 + (size_t)(j0) * D_MODEL, &Kls[buf][(tid      ) * 8]); \
        GLD16(kg1 + (size_t)(j0) * D_MODEL, &Kls[buf][(tid + 128) * 8]); \
        GLD16(kg2 + (size_t)(j0) * D_MODEL, &Kls[buf][(tid + 256) * 8]); \
        GLD16(kg3 + (size_t)(j0) * D_MODEL, &Kls[buf][(tid + 384) * 8]); \
        GLD16(vg0 + (j0),                   &Vls[buf][(tid      ) * 8]); \
        GLD16(vg1 + (j0),                   &Vls[buf][(tid + 128) * 8]); \
        GLD16(vg2 + (j0),                   &Vls[buf][(tid + 256) * 8]); \
        GLD16(vg3 + (j0),                   &Vls[buf][(tid + 384) * 8]); \
    } while (0)
#else
#define STAGE(buf, j0) do { \
        short8 a0_ = *(const short8*)(kg0 + (size_t)(j0) * D_MODEL); \
        short8 a1_ = *(const short8*)(kg1 + (size_t)(j0) * D_MODEL); \
        short8 a2_ = *(const short8*)(kg2 + (size_t)(j0) * D_MODEL); \
        short8 a3_ = *(const short8*)(kg3 + (size_t)(j0) * D_MODEL); \
        half8  c0_ = *(const half8*)(vg0 + (j0)); \
        half8  c1_ = *(const half8*)(vg1 + (j0)); \
        half8  c2_ = *(const half8*)(vg2 + (j0)); \
        half8  c3_ = *(const half8*)(vg3 + (j0)); \
        *(short8*)&Kls[buf][(tid      ) * 8] = a0_; \
        *(short8*)&Kls[buf][(tid + 128) * 8] = a1_; \
        *(short8*)&Kls[buf][(tid + 256) * 8] = a2_; \
        *(short8*)&Kls[buf][(tid + 384) * 8] = a3_; \
        *(half8*)&Vls[buf][(tid      ) * 8] = c0_; \
        *(half8*)&Vls[buf][(tid + 128) * 8] = c1_; \
        *(half8*)&Vls[buf][(tid + 256) * 8] = c2_; \
        *(half8*)&Vls[buf][(tid + 384) * 8] = c3_; \
    } while (0)
#endif

    float m_ = -1e30f;
    f32x4 lacc[2];
    f32x4 o[2][4];
#pragma unroll
    for (int qg = 0; qg < 2; ++qg) {
        lacc[qg] = (f32x4){0.f, 0.f, 0.f, 0.f};
#pragma unroll
        for (int t = 0; t < 4; ++t) o[qg][t] = (f32x4){0.f, 0.f, 0.f, 0.f};
    }

    STAGE(0, 0);
    __syncthreads();

    for (int jt = 0; jt < SEQ / 64; ++jt) {
        const int cur = jt & 1;
        if (jt + 1 < SEQ / 64) STAGE(cur ^ 1, (jt + 1) * 64);

        // ---- S^T = K * Q^T (exp2-domain): each kf feeds both qg ----
        f32x4 s4[2][4];
#pragma unroll
        for (int qg = 0; qg < 2; ++qg)
#pragma unroll
        for (int t = 0; t < 4; ++t) s4[qg][t] = (f32x4){0.f, 0.f, 0.f, 0.f};
#pragma unroll
        for (int k0h = 0; k0h < 2; ++k0h)
#pragma unroll
        for (int t = 0; t < 4; ++t) {
            const int krow = t*16 + l16;
            short8 kf = *(const short8*)&Kls[cur][krow*64 + (((k0h*4 + quad) ^ (krow & 7)) * 8)];
#pragma unroll
            for (int qg = 0; qg < 2; ++qg)
                s4[qg][t] = __builtin_amdgcn_mfma_f32_16x16x32_bf16(kf, qf[qg][k0h], s4[qg][t], 0, 0, 0);
        }

        // ---- lazy wave-shared max over all 32 q ----
        float mx = s4[0][0][0];
#pragma unroll
        for (int qg = 0; qg < 2; ++qg)
#pragma unroll
        for (int t = 0; t < 4; ++t)
#pragma unroll
        for (int r = 0; r < 4; ++r) mx = fmaxf(mx, s4[qg][t][r]);
        if (__any(mx > m_)) {
#pragma unroll
            for (int d = 1; d < 64; d <<= 1) mx = fmaxf(mx, __shfl_xor(mx, d));
            const float mn = fmaxf(m_, mx);
            const float al = EXP2(m_ - mn);
#pragma unroll
            for (int qg = 0; qg < 2; ++qg) {
#pragma unroll
                for (int t = 0; t < 4; ++t) {
                    o[qg][t][0] *= al; o[qg][t][1] *= al;
                    o[qg][t][2] *= al; o[qg][t][3] *= al;
                }
                lacc[qg][0] *= al; lacc[qg][1] *= al;
                lacc[qg][2] *= al; lacc[qg][3] *= al;
            }
            m_ = mn;
        }

        // ---- P = exp2(S - m), f16 (packed cvt), XOR-swizzled LDS ----
#pragma unroll
        for (int qg = 0; qg < 2; ++qg)
#pragma unroll
        for (int t = 0; t < 4; ++t) {
            union { fp16x2 h2[2]; int2 v; } u4;
#ifdef HAS_PKRTZ
            u4.h2[0] = __builtin_amdgcn_cvt_pkrtz(EXP2(s4[qg][t][0] - m_), EXP2(s4[qg][t][1] - m_));
            u4.h2[1] = __builtin_amdgcn_cvt_pkrtz(EXP2(s4[qg][t][2] - m_), EXP2(s4[qg][t][3] - m_));
#else
            u4.h2[0] = (fp16x2){ (__fp16)EXP2(s4[qg][t][0] - m_), (__fp16)EXP2(s4[qg][t][1] - m_) };
            u4.h2[1] = (fp16x2){ (__fp16)EXP2(s4[qg][t][2] - m_), (__fp16)EXP2(s4[qg][t][3] - m_) };
#endif
            const int c = (t*2 + (quad >> 1)) ^ (l16 & 7);
            *(int2*)&Pls[wave][(qg*16 + l16)*64 + c*8 + (quad & 1)*4] = u4.v;
        }

        // ---- O^T += V^T * P^T ; l += ones * P^T: each vf feeds both qg ----
#pragma unroll
        for (int k0h = 0; k0h < 2; ++k0h) {
            const int pc = (k0h*4 + quad) ^ (l16 & 7);
            half8 pf[2];
#pragma unroll
            for (int qg = 0; qg < 2; ++qg) {
                pf[qg] = *(half8*)&Pls[wave][(qg*16 + l16)*64 + pc*8];
                lacc[qg] = __builtin_amdgcn_mfma_f32_16x16x32_f16(ones, pf[qg], lacc[qg], 0, 0, 0);
            }
#pragma unroll
            for (int t = 0; t < 4; ++t) {
                const int vrow = t*16 + l16;
                half8 vf = *(const half8*)&Vls[cur][vrow*64 + (((k0h*4 + quad) ^ (vrow & 7)) * 8)];
#pragma unroll
                for (int qg = 0; qg < 2; ++qg)
                    o[qg][t] = __builtin_amdgcn_mfma_f32_16x16x32_f16(vf, pf[qg], o[qg][t], 0, 0, 0);
            }
        }

        __syncthreads();
    }

    // ---- normalize + packed bf16 stores ----
#pragma unroll
    for (int qg = 0; qg < 2; ++qg) {
        const float inv = 1.0f / lacc[qg][0];
        const size_t rowp = (bS + qbase + qg*16 + l16) * D_MODEL + h*HD;
#pragma unroll
        for (int t = 0; t < 4; ++t) {
            union { short s4v[4]; int2 v; } u4;
#pragma unroll
            for (int r = 0; r < 4; ++r) u4.s4v[r] = f2bf(o[qg][t][r] * inv);
            *(int2*)(ctx + rowp + t*16 + quad*4) = u4.v;
        }
    }
#undef STAGE
}

// ---------------------------------------------------------------------------
extern "C" void kernel_launch(void* const* d_in, const int* in_sizes, int n_in,
                              void* d_out, int out_size, void* d_ws, size_t ws_size,
                              hipStream_t stream)
{
    int* flag = (int*)d_ws;
    short* xc = (short*)((char*)d_ws + 64);
    short* Wt = xc + NX;                 // 4 transposed weights q|k|v|o
    short* bc = Wt + 4 * NW;             // biases q|k|v|o
    short* qb = bc + 4 * D_MODEL;
    short* kb = qb + NX;
    _Float16* Vt = (_Float16*)(kb + NX); // [24][64][2048] f16
    short* cb = (short*)(Vt + NX);

    fused_conv<<<3649, 256, 0, stream>>>(d_in[0],
                                         d_in[1], d_in[3], d_in[5], d_in[7],
                                         d_in[2], d_in[4], d_in[6], d_in[8],
                                         xc, Wt, bc, flag);

    qkv_gemm<<<dim3(NTOK/128, 2304/128), 256, 0, stream>>>(xc, Wt, bc, qb, kb, Vt);

    attn_mfma<<<768, 128, 0, stream>>>(qb, kb, Vt, cb);

    out_gemm<<<dim3(NTOK/64, D_MODEL/64), 256, 0, stream>>>(cb, Wt + 3*NW, bc + 3*D_MODEL, d_out, flag);
}

// Round 14
// 178.694 us; speedup vs baseline: 1.0579x; 1.0579x over previous
//
#include <hip/hip_runtime.h>
#include <hip/hip_bf16.h>
#include <hip/hip_fp16.h>

#define D_MODEL 768
#define NHEADS  12
#define HD      64
#define BATCH   2
#define SEQ     2048
#define NTOK    (BATCH*SEQ)   // 4096
#define NX      ((size_t)NTOK * D_MODEL)     // 3,145,728
#define NW      ((size_t)D_MODEL * D_MODEL)  // 589,824
#define SC_LOG2 0.18033688f   // (1/8) * log2(e), folded into Wq/bq

typedef __attribute__((ext_vector_type(8))) short    short8;
typedef __attribute__((ext_vector_type(8))) _Float16 half8;
typedef __attribute__((ext_vector_type(2))) __fp16   fp16x2;
typedef __attribute__((ext_vector_type(4))) float    f32x4;

__device__ __forceinline__ float bf2f(short s) {
    union { unsigned u; float f; } c;
    c.u = ((unsigned)(unsigned short)s) << 16;
    return c.f;
}
__device__ __forceinline__ short f2bf(float f) {
    __hip_bfloat16 h = __float2bfloat16(f);
    return *(short*)&h;
}

#ifdef __has_builtin
#if __has_builtin(__builtin_amdgcn_global_load_lds)
#define HAS_GLD 1
#endif
#if __has_builtin(__builtin_amdgcn_exp2f)
#define EXP2(x) __builtin_amdgcn_exp2f(x)
#else
#define EXP2(x) exp2f(x)
#endif
#if __has_builtin(__builtin_amdgcn_cvt_pkrtz)
#define HAS_PKRTZ 1
#endif
#else
#define EXP2(x) exp2f(x)
#endif
#ifdef HAS_GLD
#define GLD16(gp, lp) __builtin_amdgcn_global_load_lds( \
    (const __attribute__((address_space(1))) void*)(gp), \
    (__attribute__((address_space(3))) void*)(lp), 16, 0, 0)
#endif

// ---------------------------------------------------------------------------
// Fused conversion kernel (one launch): every block locally detects the input
// dtype from x's first 4096 halfwords, then converts its assigned slice.
//   blocks [0,3072):   x -> bf16 (int4-wide)
//   blocks [3072,3648): weight transpose+convert (Wq scaled by SC_LOG2)
//   block 3648:        biases (bq scaled) + persist flag for out_gemm
// ---------------------------------------------------------------------------
__global__ __launch_bounds__(256) void fused_conv(
        const void* __restrict__ xin,
        const void* __restrict__ w0, const void* __restrict__ w1,
        const void* __restrict__ w2, const void* __restrict__ w3,
        const void* __restrict__ b0, const void* __restrict__ b1,
        const void* __restrict__ b2, const void* __restrict__ b3,
        short* __restrict__ xc, short* __restrict__ wt,
        short* __restrict__ bc, int* __restrict__ flag)
{
    __shared__ int red[256];
    __shared__ float T[64][65];
    const int tid = threadIdx.x;
    const int F = blockIdx.x;

    {
        const short* xs = (const short*)xin;
        int maxe = 0;
#pragma unroll
        for (int u = 0; u < 16; ++u) {
            int e = ((unsigned short)xs[tid * 16 + u] >> 7) & 0xFF;
            maxe = max(maxe, e);
        }
        red[tid] = maxe;
        __syncthreads();
        for (int s = 128; s > 0; s >>= 1) {
            if (tid < s) red[tid] = max(red[tid], red[tid + s]);
            __syncthreads();
        }
    }
    const bool isf = (red[0] > 140);

    if (F < 3072) {
        const int i = F * 256 + tid;
        if (isf) {
            float4 f = ((const float4*)xin)[i];
            short4 o = { f2bf(f.x), f2bf(f.y), f2bf(f.z), f2bf(f.w) };
            ((short4*)xc)[i] = o;
        } else {
            ((short4*)xc)[i] = ((const short4*)xin)[i];
        }
    } else if (F < 3648) {
        const int G = F - 3072;
        const int z = G / 144, rr = G % 144;
        const int k0 = (rr % 12) * 64, n0 = (rr / 12) * 64;
        const void* src = (z == 0) ? w0 : (z == 1) ? w1 : (z == 2) ? w2 : w3;
        const float sc = (z == 0) ? SC_LOG2 : 1.0f;
        const int la = tid & 15, lb = tid >> 4;
#pragma unroll
        for (int u = 0; u < 4; ++u) {
            const int kr = (lb & 3) + 4 * u + 16 * (lb >> 2);
            if (isf) {
                float4 f = *(const float4*)((const float*)src + (size_t)(k0 + kr) * D_MODEL + n0 + la * 4);
                T[kr][la*4+0] = f.x; T[kr][la*4+1] = f.y; T[kr][la*4+2] = f.z; T[kr][la*4+3] = f.w;
            } else {
                short4 s = *(const short4*)((const short*)src + (size_t)(k0 + kr) * D_MODEL + n0 + la * 4);
                T[kr][la*4+0] = bf2f(s.x); T[kr][la*4+1] = bf2f(s.y);
                T[kr][la*4+2] = bf2f(s.z); T[kr][la*4+3] = bf2f(s.w);
            }
        }
        __syncthreads();
#pragma unroll
        for (int u = 0; u < 4; ++u) {
            const int nr = (lb & 3) + 4 * u + 16 * (lb >> 2);
            short4 o = { f2bf(T[la*4+0][nr] * sc), f2bf(T[la*4+1][nr] * sc),
                         f2bf(T[la*4+2][nr] * sc), f2bf(T[la*4+3][nr] * sc) };
            *(short4*)(wt + (size_t)z * NW + (size_t)(n0 + nr) * D_MODEL + k0 + la * 4) = o;
        }
    } else {
        if (tid == 0) *flag = isf ? 1 : 0;
        const void* srcs[4] = { b0, b1, b2, b3 };
        for (int z = 0; z < 4; ++z) {
            const float sc = (z == 0) ? SC_LOG2 : 1.0f;
            for (int i = tid; i < D_MODEL; i += 256) {
                float v = isf ? ((const float*)srcs[z])[i] : bf2f(((const short*)srcs[z])[i]);
                bc[z * D_MODEL + i] = f2bf(v * sc);
            }
        }
    }
}

// ---------------------------------------------------------------------------
// Fused QKV GEMM v14: 64M x 128N tiles -> grid 64x18 = 1152 blocks (4.5/CU,
// was 576 = 2.25/CU with 33% tail imbalance). Wave = 32M x 64N (2 mt x 4 nt).
// Double-buffered GLD16. V segment -> Vt f16 [bh][dim][SEQ] via single-pass
// LDS transpose (128 dims x 64 toks, stride 72).
// ---------------------------------------------------------------------------
__global__ __launch_bounds__(256) void qkv_gemm(const short* __restrict__ X,
                                                const short* __restrict__ Wt,
                                                const short* __restrict__ bias,
                                                short* __restrict__ qb,
                                                short* __restrict__ kb,
                                                _Float16* __restrict__ Vt)
{
    __shared__ __align__(16) char shbuf[24576];
    short* Als = (short*)shbuf;              // [2][2048]
    short* Bls = (short*)(shbuf + 8192);     // [2][4096]
    _Float16* T = (_Float16*)shbuf;          // epilogue: 128*72 f16 = 18432 B

    const int tid = threadIdx.x;
    const int wave = tid >> 6, lane = tid & 63;
    const int quad = lane >> 4, l16 = lane & 15;
    const int wm = wave & 1, wn = wave >> 1;
    const int m0 = blockIdx.x * 64;
    const int ng = blockIdx.y * 128;

    f32x4 acc[2][4];
#pragma unroll
    for (int nt = 0; nt < 4; ++nt) {
        const float bv = bf2f(bias[ng + wn*64 + nt*16 + l16]);
#pragma unroll
        for (int mt = 0; mt < 2; ++mt) acc[mt][nt] = (f32x4){bv, bv, bv, bv};
    }

    const int row = tid >> 2, ch = (tid & 3) * 8;
#ifdef HAS_GLD
#define QSTAGE(buf, k0) do { \
        GLD16(X  + (size_t)(m0 + row)      * D_MODEL + (k0) + ch, &Als[(buf)*2048 + tid*8]); \
        GLD16(Wt + (size_t)(ng + row)      * D_MODEL + (k0) + ch, &Bls[(buf)*4096 + tid*8]); \
        GLD16(Wt + (size_t)(ng + 64 + row) * D_MODEL + (k0) + ch, &Bls[(buf)*4096 + 2048 + tid*8]); \
    } while (0)
#else
#define QSTAGE(buf, k0) do { \
        short8 r0 = *(const short8*)(X  + (size_t)(m0 + row)      * D_MODEL + (k0) + ch); \
        short8 r2 = *(const short8*)(Wt + (size_t)(ng + row)      * D_MODEL + (k0) + ch); \
        short8 r3 = *(const short8*)(Wt + (size_t)(ng + 64 + row) * D_MODEL + (k0) + ch); \
        *(short8*)&Als[(buf)*2048 + tid*8] = r0; \
        *(short8*)&Bls[(buf)*4096 + tid*8] = r2; \
        *(short8*)&Bls[(buf)*4096 + 2048 + tid*8] = r3; \
    } while (0)
#endif

    QSTAGE(0, 0);
    __syncthreads();

    for (int ks = 0; ks < 24; ++ks) {
        const int cur = ks & 1;
        if (ks + 1 < 24) QSTAGE(cur ^ 1, (ks + 1) * 32);

        short8 a[2], b[4];
#pragma unroll
        for (int mt = 0; mt < 2; ++mt)
            a[mt] = *(const short8*)&Als[cur*2048 + (wm*32 + mt*16 + l16) * 32 + quad*8];
#pragma unroll
        for (int nt = 0; nt < 4; ++nt)
            b[nt] = *(const short8*)&Bls[cur*4096 + (wn*64 + nt*16 + l16) * 32 + quad*8];
#pragma unroll
        for (int mt = 0; mt < 2; ++mt)
#pragma unroll
        for (int nt = 0; nt < 4; ++nt)
            acc[mt][nt] = __builtin_amdgcn_mfma_f32_16x16x32_bf16(a[mt], b[nt], acc[mt][nt], 0, 0, 0);

        __syncthreads();
    }
#undef QSTAGE

    const int seg = blockIdx.y / 6;   // 0=q, 1=k, 2=v
    if (seg < 2) {
        short* out = seg ? kb : qb;
        const int nl = ng - seg * 768;
#pragma unroll
        for (int mt = 0; mt < 2; ++mt)
#pragma unroll
        for (int nt = 0; nt < 4; ++nt) {
            const int n = nl + wn*64 + nt*16 + l16;
#pragma unroll
            for (int r = 0; r < 4; ++r) {
                const int m = m0 + wm*32 + mt*16 + quad*4 + r;
                out[(size_t)m * D_MODEL + n] = f2bf(acc[mt][nt][r]);
            }
        }
    } else {
        // single-pass LDS transpose: T[dim128][tok64+pad8]
        const int batch = m0 >> 11, tokb = m0 & (SEQ - 1);
#pragma unroll
        for (int nt = 0; nt < 4; ++nt) {
            const int dim_l = wn*64 + nt*16 + l16;
#pragma unroll
            for (int mt = 0; mt < 2; ++mt) {
                const int tok_l = wm*32 + mt*16 + quad*4;
                union { _Float16 h4[4]; int2 v; } u;
#pragma unroll
                for (int r = 0; r < 4; ++r) u.h4[r] = (_Float16)acc[mt][nt][r];
                *(int2*)&T[dim_l * 72 + tok_l] = u.v;
            }
        }
        __syncthreads();
#pragma unroll
        for (int u = 0; u < 4; ++u) {
            const int slot = tid + u * 256;           // 0..1023
            const int drow = slot >> 3, chk = slot & 7;
            int4 val = *(const int4*)&T[drow * 72 + chk * 8];
            const int dim_g = ng - 1536 + drow;
            const int h = dim_g >> 6, d = dim_g & 63;
            *(int4*)(Vt + ((size_t)(batch * NHEADS + h) * HD + d) * SEQ + tokb + chk*8) = val;
        }
    }
}

// ---------------------------------------------------------------------------
// Output projection, 64x64 tiles, double-buffered staging.
// ---------------------------------------------------------------------------
__global__ __launch_bounds__(256) void out_gemm(const short* __restrict__ X,
                                                const short* __restrict__ Wt,
                                                const short* __restrict__ bias,
                                                void* __restrict__ outv,
                                                const int* __restrict__ flag)
{
    __shared__ short Als[2][2048];
    __shared__ short Bls[2][2048];

    const int tid = threadIdx.x;
    const int wave = tid >> 6, lane = tid & 63;
    const int quad = lane >> 4, l16 = lane & 15;
    const int m0 = blockIdx.x * 64;
    const int n0 = blockIdx.y * 64;

    f32x4 acc[4];
#pragma unroll
    for (int nt = 0; nt < 4; ++nt) {
        const float bv = bf2f(bias[n0 + nt*16 + l16]);
        acc[nt] = (f32x4){bv, bv, bv, bv};
    }

    const int row = tid >> 2, ch = (tid & 3) * 8;
#ifdef HAS_GLD
#define OSTAGE(buf, k0) do { \
        GLD16(X  + (size_t)(m0 + row) * D_MODEL + (k0) + ch, &Als[buf][tid*8]); \
        GLD16(Wt + (size_t)(n0 + row) * D_MODEL + (k0) + ch, &Bls[buf][tid*8]); \
    } while (0)
#else
#define OSTAGE(buf, k0) do { \
        short8 r0 = *(const short8*)(X  + (size_t)(m0 + row) * D_MODEL + (k0) + ch); \
        short8 r1 = *(const short8*)(Wt + (size_t)(n0 + row) * D_MODEL + (k0) + ch); \
        *(short8*)&Als[buf][tid*8] = r0; \
        *(short8*)&Bls[buf][tid*8] = r1; \
    } while (0)
#endif

    OSTAGE(0, 0);
    __syncthreads();

    for (int ks = 0; ks < 24; ++ks) {
        const int cur = ks & 1;
        if (ks + 1 < 24) OSTAGE(cur ^ 1, (ks + 1) * 32);

        short8 a = *(const short8*)&Als[cur][(wave*16 + l16) * 32 + quad*8];
#pragma unroll
        for (int nt = 0; nt < 4; ++nt) {
            short8 b = *(const short8*)&Bls[cur][(nt*16 + l16) * 32 + quad*8];
            acc[nt] = __builtin_amdgcn_mfma_f32_16x16x32_bf16(a, b, acc[nt], 0, 0, 0);
        }
        __syncthreads();
    }
#undef OSTAGE

    const bool outf32 = (*flag != 0);
#pragma unroll
    for (int nt = 0; nt < 4; ++nt) {
        const int n = n0 + nt*16 + l16;
#pragma unroll
        for (int r = 0; r < 4; ++r) {
            const int m = m0 + wave*16 + quad*4 + r;
            const size_t idx = (size_t)m * D_MODEL + n;
            if (outf32) ((float*)outv)[idx] = acc[nt][r];
            else        ((short*)outv)[idx] = f2bf(acc[nt][r]);
        }
    }
}

// ---------------------------------------------------------------------------
// Flash attention (exact R12 kernel — 58 µs verified): 4 waves x 16 q,
// LDS-staged double-buffered K/V, exp2-domain logits, lazy __any max,
// EXP2 + cvt_pkrtz, MFMA row-sum, XCD-locality swizzle. LDS 40 KB.
// ---------------------------------------------------------------------------
__global__ __launch_bounds__(256) void attn_mfma(const short* __restrict__ q,
                                                 const short* __restrict__ k,
                                                 const _Float16* __restrict__ Vt,
                                                 short* __restrict__ ctx)
{
    __shared__ short    Kls[2][64 * 64];       // swizzled [key][chunk], 8 KB/buf
    __shared__ _Float16 Vls[2][64 * 64];       // swizzled [dim][chunk], 8 KB/buf
    __shared__ _Float16 Pls[4][16 * 64];       // per-wave, XOR-swizzled, 8 KB

    const int tid  = threadIdx.x;
    const int wave = tid >> 6, lane = tid & 63;
    const int quad = lane >> 4, l16 = lane & 15;

    const int F = blockIdx.x;
    const int xcd = F & 7, slot = F >> 3;
    const int bh = xcd * 3 + (slot >> 5);
    const int q0 = (slot & 31) * 64;
    const int b = bh / NHEADS, h = bh % NHEADS;
    const size_t bS = (size_t)b * SEQ;
    const int myq = q0 + wave * 16 + l16;

    short8 qf[2];
#pragma unroll
    for (int k0h = 0; k0h < 2; ++k0h)
        qf[k0h] = *(const short8*)(q + (bS + myq) * D_MODEL + h*HD + k0h*32 + quad*8);

    half8 ones;
#pragma unroll
    for (int j = 0; j < 8; ++j) ones[j] = (_Float16)1.0f;

    const int s0 = tid, s1 = tid + 256;
    const int kr0 = s0 >> 3, kc0 = (s0 & 7) ^ (kr0 & 7);
    const int kr1 = s1 >> 3, kc1 = (s1 & 7) ^ (kr1 & 7);
    const short*    kg0 = k  + (bS + kr0) * D_MODEL + h*HD + kc0*8;
    const short*    kg1 = k  + (bS + kr1) * D_MODEL + h*HD + kc1*8;
    const _Float16* vg0 = Vt + ((size_t)bh * HD + kr0) * SEQ + kc0*8;
    const _Float16* vg1 = Vt + ((size_t)bh * HD + kr1) * SEQ + kc1*8;

#ifdef HAS_GLD
#define STAGE(buf, j0) do { \
        GLD16(kg0 + (size_t)(j0) * D_MODEL, &Kls[buf][s0 * 8]); \
        GLD16(kg1 + (size_t)(j0) * D_MODEL, &Kls[buf][s1 * 8]); \
        GLD16(vg0 + (j0),                   &Vls[buf][s0 * 8]); \
        GLD16(vg1 + (j0),                   &Vls[buf][s1 * 8]); \
    } while (0)
#else
#define STAGE(buf, j0) do { \
        short8 a_ = *(const short8*)(kg0 + (size_t)(j0) * D_MODEL); \
        short8 b_ = *(const short8*)(kg1 + (size_t)(j0) * D_MODEL); \
        half8  c_ = *(const half8*)(vg0 + (j0)); \
        half8  d_ = *(const half8*)(vg1 + (j0)); \
        *(short8*)&Kls[buf][s0 * 8] = a_;  *(short8*)&Kls[buf][s1 * 8] = b_; \
        *(half8*)&Vls[buf][s0 * 8] = c_;   *(half8*)&Vls[buf][s1 * 8] = d_; \
    } while (0)
#endif

    float m_ = -1e30f;
    f32x4 lacc = (f32x4){0.f, 0.f, 0.f, 0.f};
    f32x4 o[4];
#pragma unroll
    for (int t = 0; t < 4; ++t) o[t] = (f32x4){0.f, 0.f, 0.f, 0.f};

    STAGE(0, 0);
    __syncthreads();

    for (int jt = 0; jt < SEQ / 64; ++jt) {
        const int cur = jt & 1;
        if (jt + 1 < SEQ / 64) STAGE(cur ^ 1, (jt + 1) * 64);

        // ---- S^T = K * Q^T (exp2-domain logits) ----
        f32x4 s4[4];
#pragma unroll
        for (int t = 0; t < 4; ++t) s4[t] = (f32x4){0.f, 0.f, 0.f, 0.f};
#pragma unroll
        for (int k0h = 0; k0h < 2; ++k0h)
#pragma unroll
        for (int t = 0; t < 4; ++t) {
            const int krow = t*16 + l16;
            short8 kf = *(const short8*)&Kls[cur][krow*64 + (((k0h*4 + quad) ^ (krow & 7)) * 8)];
            s4[t] = __builtin_amdgcn_mfma_f32_16x16x32_bf16(kf, qf[k0h], s4[t], 0, 0, 0);
        }

        // ---- lazy wave-shared max: reduce+rescale only on increase ----
        float mx = s4[0][0];
#pragma unroll
        for (int t = 0; t < 4; ++t)
#pragma unroll
        for (int r = 0; r < 4; ++r) mx = fmaxf(mx, s4[t][r]);
        if (__any(mx > m_)) {
#pragma unroll
            for (int d = 1; d < 64; d <<= 1) mx = fmaxf(mx, __shfl_xor(mx, d));
            const float mn = fmaxf(m_, mx);
            const float al = EXP2(m_ - mn);
#pragma unroll
            for (int t = 0; t < 4; ++t) {
                o[t][0] *= al; o[t][1] *= al; o[t][2] *= al; o[t][3] *= al;
            }
            lacc[0] *= al; lacc[1] *= al; lacc[2] *= al; lacc[3] *= al;
            m_ = mn;
        }

        // ---- P = exp2(S - m), f16 (packed cvt), XOR-swizzled LDS ----
#pragma unroll
        for (int t = 0; t < 4; ++t) {
            union { fp16x2 h2[2]; int2 v; } u4;
#ifdef HAS_PKRTZ
            u4.h2[0] = __builtin_amdgcn_cvt_pkrtz(EXP2(s4[t][0] - m_), EXP2(s4[t][1] - m_));
            u4.h2[1] = __builtin_amdgcn_cvt_pkrtz(EXP2(s4[t][2] - m_), EXP2(s4[t][3] - m_));
#else
            u4.h2[0] = (fp16x2){ (__fp16)EXP2(s4[t][0] - m_), (__fp16)EXP2(s4[t][1] - m_) };
            u4.h2[1] = (fp16x2){ (__fp16)EXP2(s4[t][2] - m_), (__fp16)EXP2(s4[t][3] - m_) };
#endif
            const int c = (t*2 + (quad >> 1)) ^ (l16 & 7);
            *(int2*)&Pls[wave][l16*64 + c*8 + (quad & 1)*4] = u4.v;
        }

        // ---- O^T += V^T * P^T ; l += ones * P^T (MFMA pipe) ----
#pragma unroll
        for (int k0h = 0; k0h < 2; ++k0h) {
            const int pc = (k0h*4 + quad) ^ (l16 & 7);
            half8 pf = *(half8*)&Pls[wave][l16*64 + pc*8];
            lacc = __builtin_amdgcn_mfma_f32_16x16x32_f16(ones, pf, lacc, 0, 0, 0);
#pragma unroll
            for (int t = 0; t < 4; ++t) {
                const int vrow = t*16 + l16;
                half8 vf = *(const half8*)&Vls[cur][vrow*64 + (((k0h*4 + quad) ^ (vrow & 7)) * 8)];
                o[t] = __builtin_amdgcn_mfma_f32_16x16x32_f16(vf, pf, o[t], 0, 0, 0);
            }
        }

        __syncthreads();
    }

    // ---- normalize + packed bf16 stores ----
    const float inv = 1.0f / lacc[0];
    const size_t rowp = (bS + myq) * D_MODEL + h*HD;
#pragma unroll
    for (int t = 0; t < 4; ++t) {
        union { short s4v[4]; int2 v; } u4;
#pragma unroll
        for (int r = 0; r < 4; ++r) u4.s4v[r] = f2bf(o[t][r] * inv);
        *(int2*)(ctx + rowp + t*16 + quad*4) = u4.v;
    }
#undef STAGE
}

// ---------------------------------------------------------------------------
extern "C" void kernel_launch(void* const* d_in, const int* in_sizes, int n_in,
                              void* d_out, int out_size, void* d_ws, size_t ws_size,
                              hipStream_t stream)
{
    int* flag = (int*)d_ws;
    short* xc = (short*)((char*)d_ws + 64);
    short* Wt = xc + NX;                 // 4 transposed weights q|k|v|o
    short* bc = Wt + 4 * NW;             // biases q|k|v|o
    short* qb = bc + 4 * D_MODEL;
    short* kb = qb + NX;
    _Float16* Vt = (_Float16*)(kb + NX); // [24][64][2048] f16
    short* cb = (short*)(Vt + NX);

    fused_conv<<<3649, 256, 0, stream>>>(d_in[0],
                                         d_in[1], d_in[3], d_in[5], d_in[7],
                                         d_in[2], d_in[4], d_in[6], d_in[8],
                                         xc, Wt, bc, flag);

    qkv_gemm<<<dim3(NTOK/64, 2304/128), 256, 0, stream>>>(xc, Wt, bc, qb, kb, Vt);

    attn_mfma<<<768, 256, 0, stream>>>(qb, kb, Vt, cb);

    out_gemm<<<dim3(NTOK/64, D_MODEL/64), 256, 0, stream>>>(cb, Wt + 3*NW, bc + 3*D_MODEL, d_out, flag);
}